// Round 14
// baseline (265.396 us; speedup 1.0000x reference)
//
#include <hip/hip_runtime.h>
#include <cmath>

#define B_  16
#define C_  256
#define H_  1024
#define S_  1024
#define E_  512
#define NH_ 8
#define DD_ 512
#define DS_ 64
#define HD_ 64
#define S1_ 1025
#define RELM 2048
#define SV  1032   // vT row stride (tokens), 16B-aligned

typedef __attribute__((ext_vector_type(8))) short bf16x8;
typedef __attribute__((ext_vector_type(4))) float f32x4;

__device__ __forceinline__ unsigned short f2bf(float f) {
    unsigned u = __float_as_uint(f);
    u += 0x7fffu + ((u >> 16) & 1u);   // RNE
    return (unsigned short)(u >> 16);
}

#if __has_builtin(__builtin_amdgcn_exp2f)
#define EXP2F(x) __builtin_amdgcn_exp2f(x)
#else
#define EXP2F(x) exp2f(x)
#endif

// async global->LDS, 16B per lane (m97 pattern)
__device__ __forceinline__ void gl2lds16(const unsigned short* g, unsigned short* l) {
#if __has_builtin(__builtin_amdgcn_global_load_lds)
    __builtin_amdgcn_global_load_lds(
        (const __attribute__((address_space(1))) void*)g,
        (__attribute__((address_space(3))) void*)l, 16, 0, 0);
#else
    const int ln = threadIdx.x & 63;
    *(bf16x8*)(l + ln * 8) = *(const bf16x8*)g;
#endif
}

__device__ __forceinline__ void conv8(const float* __restrict__ src,
                                      unsigned short* __restrict__ dst, int i) {
    float4 a = *(const float4*)(src + i);
    float4 b = *(const float4*)(src + i + 4);
    bf16x8 o;
    ((unsigned short*)&o)[0] = f2bf(a.x); ((unsigned short*)&o)[1] = f2bf(a.y);
    ((unsigned short*)&o)[2] = f2bf(a.z); ((unsigned short*)&o)[3] = f2bf(a.w);
    ((unsigned short*)&o)[4] = f2bf(b.x); ((unsigned short*)&o)[5] = f2bf(b.y);
    ((unsigned short*)&o)[6] = f2bf(b.z); ((unsigned short*)&o)[7] = f2bf(b.w);
    *(bf16x8*)(dst + i) = o;
}

// 64-lane butterfly sum
__device__ __forceinline__ float wred(float p) {
#pragma unroll
    for (int off = 32; off; off >>= 1) p += __shfl_down(p, off, 64);
    return p;
}

// ---- conv kernel + stat stage + x transpose ----
// blocks [0,512): grid-stride conv8 | [512,576): stat matvec | [576,1600): xpose
#define U_DYN 1048576
#define U_KV  1114112
#define U_Q   1146880
#define U_TOT 1163264
__global__ __launch_bounds__(512)
void prep_conv(const float* __restrict__ dyn, unsigned short* __restrict__ dyn16,
               const float* __restrict__ ipW, unsigned short* __restrict__ ipWq16,
               unsigned short* __restrict__ ipWkv16,
               const float* __restrict__ ctxW, unsigned short* __restrict__ ctxW16,
               const float* __restrict__ statIn,
               const float* __restrict__ stat_W, const float* __restrict__ stat_b,
               float* __restrict__ st_g, unsigned short* __restrict__ st16,
               const float* __restrict__ x, unsigned short* __restrict__ xT)
{
    __shared__ float tle[64][65];
    const int blk = blockIdx.x;
    const int t = threadIdx.x;
    if (blk < 512) {
        const float* ipWkv = ipW + (size_t)E_ * E_;
        const int stride = 512 * 512;
        for (int u = blk * 512 + t; u < U_TOT; u += stride) {
            if (u < U_DYN)      conv8(dyn,   dyn16,   u * 8);
            else if (u < U_KV)  conv8(ipWkv, ipWkv16, (u - U_DYN) * 8);
            else if (u < U_Q)   conv8(ipW,   ipWq16,  (u - U_KV) * 8);
            else                conv8(ctxW,  ctxW16,  (u - U_Q) * 8);
        }
    } else if (blk < 576) {
        // stat[b][r] = stat_b[r] + statIn[b] . stat_W[r]  (K=64 = one elem/lane)
        const int sub = blk - 512;
        const int b = sub >> 2;
        const int q = sub & 3;          // row quarter (128 rows)
        const int wv = t >> 6;
        const int ln = t & 63;
        const float sv = statIn[b * DS_ + ln];
#pragma unroll 4
        for (int i = 0; i < 16; i++) {
            const int r = q * 128 + wv * 16 + i;
            const float p = wred(stat_W[(size_t)r * DS_ + ln] * sv);
            if (ln == 0) {
                const float v = p + stat_b[r];
                st_g[(size_t)b * E_ + r] = v;
                st16[(size_t)b * E_ + r] = f2bf(v);
            }
        }
    } else {
        // xT[b*H + h][c] = bf16(x[b][c][h]) — 64x64 tile, 512 threads (2 rows/thread)
        const int sub = blk - 576;
        const int b  = sub >> 6;
        const int c0 = ((sub >> 4) & 3) * 64;
        const int h0 = (sub & 15) * 64;
        const int tx = t & 15, ty = t >> 4;          // ty in [0,32)
#pragma unroll
        for (int i = 0; i < 2; i++) {
            const float4 v = *(const float4*)&x[((size_t)(b * C_ + c0 + ty + i * 32)) * H_ + h0 + tx * 4];
            tle[ty + i * 32][tx * 4 + 0] = v.x;
            tle[ty + i * 32][tx * 4 + 1] = v.y;
            tle[ty + i * 32][tx * 4 + 2] = v.z;
            tle[ty + i * 32][tx * 4 + 3] = v.w;
        }
        __syncthreads();
#pragma unroll
        for (int i = 0; i < 2; i++) {
            const int hh = ty + i * 32;
            ushort4 o;
            o.x = f2bf(tle[tx * 4 + 0][hh]);
            o.y = f2bf(tle[tx * 4 + 1][hh]);
            o.z = f2bf(tle[tx * 4 + 2][hh]);
            o.w = f2bf(tle[tx * 4 + 3][hh]);
            *(ushort4*)&xT[((size_t)(b * H_ + h0 + hh)) * C_ + c0 + tx * 4] = o;
        }
    }
}

// ---- misc prep: film1 (128) | rowdots (224) | transposes (160) ----
__global__ __launch_bounds__(512)
void prep_misc(const float* __restrict__ ipW, const float* __restrict__ ipb,
               const float* __restrict__ ctxW,
               const float* __restrict__ q_W, unsigned short* __restrict__ qWT16,
               const float* __restrict__ dynW, unsigned short* __restrict__ dynWT16,
               const float* __restrict__ outW, unsigned short* __restrict__ outWT16,
               const float* __restrict__ q_b, float* __restrict__ qb2,
               const float* __restrict__ dyn_b, float* __restrict__ bkv2,
               const float* __restrict__ out_b, const float* __restrict__ ctx_b,
               float* __restrict__ cb2,
               const float* __restrict__ st_g,
               const float* __restrict__ fW1, const float* __restrict__ fb1,
               float* __restrict__ h1_g)
{
    __shared__ float tle[64][65];
    const int blk = blockIdx.x;
    const int t = threadIdx.x;
    const float* ipWkv = ipW + (size_t)E_ * E_;
    const float* ipbkv = ipb + E_;

    if (blk < 128) {
        // ---- film1: h1[b][r] = leaky(fb1[r] + st[b] . fW1[r]), K=512 ----
        const int b   = blk >> 3;
        const int oct = blk & 7;        // 64-row slice
        const int wv  = t >> 6;
        const int ln  = t & 63;
        float str[8];
        *(float4*)&str[0] = *(const float4*)&st_g[(size_t)b * E_ + ln * 8];
        *(float4*)&str[4] = *(const float4*)&st_g[(size_t)b * E_ + ln * 8 + 4];
#pragma unroll 2
        for (int i = 0; i < 8; i++) {
            const int r = oct * 64 + wv * 8 + i;
            const float* wr = fW1 + (size_t)r * E_ + ln * 8;
            const float4 a = *(const float4*)wr;
            const float4 c = *(const float4*)(wr + 4);
            float p = a.x * str[0] + a.y * str[1] + a.z * str[2] + a.w * str[3]
                    + c.x * str[4] + c.y * str[5] + c.z * str[6] + c.w * str[7];
            p = wred(p);
            if (ln == 0) {
                const float v = p + fb1[r];
                h1_g[(size_t)b * E_ + r] = (v >= 0.f) ? v : 0.1f * v;
            }
        }
    } else if (blk < 352) {
        // ---- bias-fold row dots: qb2 (512) | bkv2 (1024) | cb2 (256) ----
        const int row = (blk - 128) * 8 + (t >> 6);
        const int ln  = t & 63;
        const float* src; const float* vec; float bias; float* dst;
        if (row < 512)       { src = ipW + (size_t)row * E_;            vec = q_b;   bias = ipb[row];        dst = qb2 + row; }
        else if (row < 1536) { const int n = row - 512;  src = ipWkv + (size_t)n * E_; vec = dyn_b; bias = ipbkv[n]; dst = bkv2 + n; }
        else                 { const int n = row - 1536; src = ctxW + (size_t)n * E_;  vec = out_b; bias = ctx_b[n]; dst = cb2 + n; }
        const float4 a  = *(const float4*)(src + ln * 8);
        const float4 c  = *(const float4*)(src + ln * 8 + 4);
        const float4 va = *(const float4*)(vec + ln * 8);
        const float4 vc = *(const float4*)(vec + ln * 8 + 4);
        float p = a.x * va.x + a.y * va.y + a.z * va.z + a.w * va.w
                + c.x * vc.x + c.y * vc.y + c.z * vc.z + c.w * vc.w;
        p = wred(p);
        if (ln == 0) *dst = p + bias;
    } else {
        // transpose fp32 (R x Cc) -> bf16 (Cc x R)
        const float* src; unsigned short* dst; int R, Cc, tile;
        const int tt = blk - 352;
        if (tt < 32)      { src = q_W;  dst = qWT16;   R = 512; Cc = 256; tile = tt; }
        else if (tt < 96) { src = dynW; dst = dynWT16; R = 512; Cc = 512; tile = tt - 32; }
        else              { src = outW; dst = outWT16; R = 512; Cc = 512; tile = tt - 96; }
        const int tpr = Cc / 64;                    // tiles per row-band
        const int r0 = (tile / tpr) * 64;
        const int c0 = (tile % tpr) * 64;
        const int tx = t & 15, ty = t >> 4;         // ty in [0,32)
#pragma unroll
        for (int i = 0; i < 2; i++) {
            const float4 v = *(const float4*)&src[(size_t)(r0 + ty + i * 32) * Cc + c0 + tx * 4];
            tle[ty + i * 32][tx * 4 + 0] = v.x;
            tle[ty + i * 32][tx * 4 + 1] = v.y;
            tle[ty + i * 32][tx * 4 + 2] = v.z;
            tle[ty + i * 32][tx * 4 + 3] = v.w;
        }
        __syncthreads();
#pragma unroll
        for (int i = 0; i < 2; i++) {
            const int cc = ty + i * 32;
            ushort4 o;
            o.x = f2bf(tle[tx * 4 + 0][cc]);
            o.y = f2bf(tle[tx * 4 + 1][cc]);
            o.z = f2bf(tle[tx * 4 + 2][cc]);
            o.w = f2bf(tle[tx * 4 + 3][cc]);
            *(ushort4*)&dst[(size_t)(c0 + cc) * R + r0 + tx * 4] = o;
        }
    }
}

// ---- three weight-fold GEMMs + film2 stage (blocks [48,112)) ----
// [0,8): WqW 512x256 | [8,40): Wkv2 1024x512 | [40,48): M2 256x512 | [48,112): film2
__global__ __launch_bounds__(256)
void gemm_fold3(const unsigned short* __restrict__ ipWq16, const unsigned short* __restrict__ qWT16,
                unsigned short* __restrict__ WqW16,
                const unsigned short* __restrict__ ipWkv16, const unsigned short* __restrict__ dynWT16,
                unsigned short* __restrict__ Wkv216,
                const unsigned short* __restrict__ ctxW16, const unsigned short* __restrict__ outWT16,
                unsigned short* __restrict__ M216,
                const float* __restrict__ h1_g,
                const float* __restrict__ fW2, const float* __restrict__ fb2,
                float* __restrict__ scaleB)
{
    __shared__ unsigned short At[128 * 32];
    __shared__ unsigned short Wt[128 * 32];
    const int bid = blockIdx.x;
    const int tid  = threadIdx.x;
    if (bid >= 48) {
        // ---- film2: scaleB[b][c] = 1 + tanh(fb2[c] + h1[b] . fW2[c]), K=512 ----
        const int sub = bid - 48;
        const int b = sub >> 2;
        const int q = sub & 3;          // 64-row slice
        const int wv = tid >> 6;        // 4 waves
        const int ln = tid & 63;
        float h1r[8];
        *(float4*)&h1r[0] = *(const float4*)&h1_g[(size_t)b * E_ + ln * 8];
        *(float4*)&h1r[4] = *(const float4*)&h1_g[(size_t)b * E_ + ln * 8 + 4];
#pragma unroll 2
        for (int i = 0; i < 16; i++) {
            const int c = q * 64 + wv * 16 + i;
            const float* wr = fW2 + (size_t)c * E_ + ln * 8;
            const float4 a = *(const float4*)wr;
            const float4 cc = *(const float4*)(wr + 4);
            float p = a.x * h1r[0] + a.y * h1r[1] + a.z * h1r[2] + a.w * h1r[3]
                    + cc.x * h1r[4] + cc.y * h1r[5] + cc.z * h1r[6] + cc.w * h1r[7];
            p = wred(p);
            if (ln == 0) scaleB[b * C_ + c] = 1.f + tanhf(p + fb2[c]);
        }
        return;
    }
    const unsigned short *A, *W; unsigned short* O; int N, mb, nb;
    if (bid < 8)       { A = ipWq16;  W = qWT16;   O = WqW16;  N = 256; mb = bid >> 1;       nb = bid & 1; }
    else if (bid < 40) { A = ipWkv16; W = dynWT16; O = Wkv216; N = 512; mb = (bid - 8) >> 2; nb = (bid - 8) & 3; }
    else               { A = ctxW16;  W = outWT16; O = M216;   N = 512; mb = (bid - 40) >> 2; nb = (bid - 40) & 3; }
    const int m0 = mb * 128, n0 = nb * 128;

    const int wave = tid >> 6;
    const int lane = tid & 63;
    const int quad = lane >> 4;
    const int l15  = lane & 15;
    const int rw = (wave >> 1) * 64;
    const int cw = (wave & 1) * 64;
    const int srow = lane >> 2;
    const int scol = (lane & 3) * 8;

    f32x4 acc[4][4] = {};
    for (int k0 = 0; k0 < 512; k0 += 32) {
        __syncthreads();
#pragma unroll
        for (int c = 0; c < 2; c++) {
            const int chunk = wave + c * 4;
            gl2lds16(A + (size_t)(m0 + chunk * 16 + srow) * 512 + k0 + scol, &At[chunk * 512]);
            gl2lds16(W + (size_t)(n0 + chunk * 16 + srow) * 512 + k0 + scol, &Wt[chunk * 512]);
        }
        __syncthreads();
        bf16x8 af[4], wf[4];
#pragma unroll
        for (int i = 0; i < 4; i++)
            af[i] = *(const bf16x8*)&At[(rw + i * 16 + l15) * 32 + quad * 8];
#pragma unroll
        for (int j = 0; j < 4; j++)
            wf[j] = *(const bf16x8*)&Wt[(cw + j * 16 + l15) * 32 + quad * 8];
#pragma unroll
        for (int i = 0; i < 4; i++)
#pragma unroll
            for (int j = 0; j < 4; j++)
                acc[i][j] = __builtin_amdgcn_mfma_f32_16x16x32_bf16(af[i], wf[j], acc[i][j], 0, 0, 0);
    }
#pragma unroll
    for (int i = 0; i < 4; i++)
#pragma unroll
        for (int r = 0; r < 4; r++) {
            const int mm = m0 + rw + i * 16 + quad * 4 + r;
            unsigned short* cp = O + (size_t)mm * N + n0 + cw + l15;
#pragma unroll
            for (int j = 0; j < 4; j++)
                cp[j * 16] = f2bf(acc[i][j][r]);
        }
}

// ---- merged Q + KV GEMMs, XCD-swizzled, T3/T4 minimum 2-phase pipeline ----
// STAGE(t+1) issued before compute(t); ONE barrier per K-step; LDS dbuf.
// logical t: [0,1032) kv (y=t>>3 m-panel, x=t&7 n-tile of 1024; y==128 static)
//            [1032,1544) q  (u=t-1032: m=u>>2 of 128, n=u&3 of 4), K=256
__global__ __launch_bounds__(256)
void gemm_qkv(const unsigned short* __restrict__ xT16, const unsigned short* __restrict__ WqW16,
              const float* __restrict__ qb2, unsigned short* __restrict__ q16,
              const unsigned short* __restrict__ dynA, const unsigned short* __restrict__ stA,
              const unsigned short* __restrict__ Wdyn, const unsigned short* __restrict__ Wst,
              const float* __restrict__ bdyn, const float* __restrict__ bst,
              unsigned short* __restrict__ k16, unsigned short* __restrict__ vtmp)
{
    __shared__ unsigned short At[2][128 * 32];
    __shared__ unsigned short Wt[2][128 * 32];
    const int bid0 = blockIdx.x;
    const int t = (bid0 & 7) * 193 + (bid0 >> 3);   // each XCD gets a contiguous logical band

    const int tid  = threadIdx.x;
    const int wave = tid >> 6;
    const int lane = tid & 63;
    const int quad = lane >> 4;
    const int l15  = lane & 15;
    const int rw = (wave >> 1) * 64;
    const int cw = (wave & 1) * 64;
    const int srow = lane >> 2;
    const int scol = (lane & 3) * 8;

    const unsigned short *A, *W;
    int m0, n0, K;
    bool isQ, stat = false;
    if (t < 1032) {
        const int y = t >> 3;
        stat = (y == 128);
        A = stat ? stA : dynA;
        W = stat ? Wst : Wdyn;
        m0 = stat ? 0 : y * 128;
        n0 = (t & 7) * 128;
        K = 512; isQ = false;
    } else {
        const int u = t - 1032;
        A = xT16; W = WqW16;
        m0 = (u >> 2) * 128;
        n0 = (u & 3) * 128;
        K = 256; isQ = true;
    }

    f32x4 acc[4][4] = {};
    // prologue: stage k0=0 into buffer 0
#pragma unroll
    for (int c = 0; c < 2; c++) {
        const int chunk = wave + c * 4;
        gl2lds16(A + (size_t)(m0 + chunk * 16 + srow) * K + scol, &At[0][chunk * 512]);
        gl2lds16(W + (size_t)(n0 + chunk * 16 + srow) * K + scol, &Wt[0][chunk * 512]);
    }
    int cur = 0;
    for (int k0 = 0; k0 < K; k0 += 32) {
        __syncthreads();               // stage(cur) complete (vmcnt/lgkm drain at barrier)
        if (k0 + 32 < K) {
            const int kn = k0 + 32;
#pragma unroll
            for (int c = 0; c < 2; c++) {
                const int chunk = wave + c * 4;
                gl2lds16(A + (size_t)(m0 + chunk * 16 + srow) * K + kn + scol, &At[cur ^ 1][chunk * 512]);
                gl2lds16(W + (size_t)(n0 + chunk * 16 + srow) * K + kn + scol, &Wt[cur ^ 1][chunk * 512]);
            }
        }
        bf16x8 af[4], wf[4];
#pragma unroll
        for (int i = 0; i < 4; i++)
            af[i] = *(const bf16x8*)&At[cur][(rw + i * 16 + l15) * 32 + quad * 8];
#pragma unroll
        for (int j = 0; j < 4; j++)
            wf[j] = *(const bf16x8*)&Wt[cur][(cw + j * 16 + l15) * 32 + quad * 8];
#pragma unroll
        for (int i = 0; i < 4; i++)
#pragma unroll
            for (int j = 0; j < 4; j++)
                acc[i][j] = __builtin_amdgcn_mfma_f32_16x16x32_bf16(af[i], wf[j], acc[i][j], 0, 0, 0);
        cur ^= 1;
    }

    if (isQ) {
        float bias4[4];
#pragma unroll
        for (int j = 0; j < 4; j++) bias4[j] = qb2[n0 + cw + j * 16 + l15];
#pragma unroll
        for (int i = 0; i < 4; i++) {
#pragma unroll
            for (int r = 0; r < 4; r++) {
                const int mm = m0 + rw + i * 16 + quad * 4 + r;
                unsigned short* cp = q16 + (size_t)mm * 512 + n0 + cw + l15;
#pragma unroll
                for (int j = 0; j < 4; j++)
                    cp[j * 16] = f2bf(acc[i][j][r] + bias4[j]);
            }
        }
    } else {
        const float* bias = stat ? bst : bdyn;
        const bool isV = (n0 >= 512);
        unsigned short* base = isV ? vtmp : k16;
        const int c0 = (isV ? n0 - 512 : n0) + cw + l15;
        float bias4[4];
#pragma unroll
        for (int j = 0; j < 4; j++) bias4[j] = bias[n0 + cw + j * 16 + l15];
#pragma unroll
        for (int i = 0; i < 4; i++) {
#pragma unroll
            for (int r = 0; r < 4; r++) {
                const int am = m0 + rw + i * 16 + quad * 4 + r;
                if (!stat || am < 16) {
                    const int orow = stat ? (am * S1_ + S_) : ((am >> 10) * S1_ + (am & 1023));
                    unsigned short* cp = base + (size_t)orow * 512 + c0;
#pragma unroll
                    for (int j = 0; j < 4; j++)
                        cp[j * 16] = f2bf(acc[i][j][r] + bias4[j]);
                }
            }
        }
    }
}

// ---- final GEMM (residual + FiLM scale), 64x128 tiles -> 512 blocks (2/CU) ----
__global__ __launch_bounds__(256)
void gemm_final(const unsigned short* __restrict__ A, const unsigned short* __restrict__ W,
                const float* __restrict__ bias, float* __restrict__ Cout,
                const float* __restrict__ x, const float* __restrict__ scale)
{
    __shared__ unsigned short At[64 * 32];
    __shared__ unsigned short Wt[128 * 32];
    const int tid  = threadIdx.x;
    const int wave = tid >> 6;
    const int lane = tid & 63;
    const int quad = lane >> 4;
    const int l15  = lane & 15;
    const int m0 = blockIdx.y * 64;     // C rows
    const int n0 = blockIdx.x * 128;    // H cols
    const int rw = (wave >> 1) * 32;
    const int cw = (wave & 1) * 64;
    const int zb = blockIdx.z;
    const unsigned short* Wb = W + (size_t)zb * H_ * E_;

    const int srow = lane >> 2;
    const int scol = (lane & 3) * 8;

    f32x4 acc[2][4] = {};

    for (int k0 = 0; k0 < E_; k0 += 32) {
        __syncthreads();
        // A: 64 rows = 4 chunks, one per wave; W: 128 rows = 8 chunks, 2 per wave
        gl2lds16(A  + (size_t)(m0 + wave * 16 + srow) * E_ + k0 + scol, &At[wave * 512]);
#pragma unroll
        for (int c = 0; c < 2; c++) {
            const int chunk = wave + c * 4;
            gl2lds16(Wb + (size_t)(n0 + chunk * 16 + srow) * E_ + k0 + scol, &Wt[chunk * 512]);
        }
        __syncthreads();
        bf16x8 af[2], wf[4];
#pragma unroll
        for (int i = 0; i < 2; i++)
            af[i] = *(const bf16x8*)&At[(rw + i * 16 + l15) * 32 + quad * 8];
#pragma unroll
        for (int j = 0; j < 4; j++)
            wf[j] = *(const bf16x8*)&Wt[(cw + j * 16 + l15) * 32 + quad * 8];
#pragma unroll
        for (int i = 0; i < 2; i++)
#pragma unroll
            for (int j = 0; j < 4; j++)
                acc[i][j] = __builtin_amdgcn_mfma_f32_16x16x32_bf16(af[i], wf[j], acc[i][j], 0, 0, 0);
    }

#pragma unroll
    for (int i = 0; i < 2; i++) {
#pragma unroll
        for (int r = 0; r < 4; r++) {
            const int mm = m0 + rw + i * 16 + quad * 4 + r;
            const float cb = bias[mm];
            const float sc = scale[zb * C_ + mm];
            const size_t base = ((size_t)(zb * C_ + mm)) * H_ + n0 + cw + l15;
#pragma unroll
            for (int j = 0; j < 4; j++)
                Cout[base + j * 16] = (x[base + j * 16] + acc[i][j][r] + cb) * sc;
        }
    }
}

// vT[b][d][s] = vtmp[b*1025+s][d], row stride SV, zero-fill s>=1025
__global__ __launch_bounds__(256)
void vtrans_kernel(const unsigned short* __restrict__ vtmp, unsigned short* __restrict__ vT)
{
    __shared__ unsigned short tle[64][72];
    const int b = blockIdx.z;
    const int s0 = blockIdx.x * 64;
    const int d0 = blockIdx.y * 64;
    const int tx = threadIdx.x & 15;
    const int ty = threadIdx.x >> 4;
#pragma unroll
    for (int i = 0; i < 4; i++) {
        const int s = s0 + ty + i * 16;
        ushort4 v = {0, 0, 0, 0};
        if (s < S1_)
            v = *(const ushort4*)&vtmp[((size_t)(b * S1_ + s)) * 512 + d0 + tx * 4];
        tle[ty + i * 16][tx * 4 + 0] = v.x;
        tle[ty + i * 16][tx * 4 + 1] = v.y;
        tle[ty + i * 16][tx * 4 + 2] = v.z;
        tle[ty + i * 16][tx * 4 + 3] = v.w;
    }
    __syncthreads();
    if (s0 + tx * 4 < SV) {
#pragma unroll
        for (int i = 0; i < 4; i++) {
            const int dd = ty + i * 16;
            ushort4 o;
            o.x = tle[tx * 4 + 0][dd];
            o.y = tle[tx * 4 + 1][dd];
            o.z = tle[tx * 4 + 2][dd];
            o.w = tle[tx * 4 + 3][dd];
            *(ushort4*)&vT[((size_t)(b * 512 + d0 + dd)) * SV + s0 + tx * 4] = o;
        }
    }
}

// ---- MFMA flash attention, Q-tile 128, 32-key tiles, pre-transposed V ----
// T14 async-stage (t+1 K/V loads issue before compute of t);
// poison bias + exp2; XOR-swizzled Pt; T5 setprio around MFMA clusters.
#define KS 72
#define VTS 40
#define PS 40

__global__ __launch_bounds__(256)
void attn_mfma_kernel(const unsigned short* __restrict__ q,
                      const unsigned short* __restrict__ k16,
                      const unsigned short* __restrict__ vT,
                      const float* __restrict__ bt,
                      unsigned short* __restrict__ ctx)
{
    const int blk  = blockIdx.x;
    const int qt   = 7 - (blk >> 7);
    const int pair = blk & 127;
    const int nh   = pair & 7;
    const int b    = pair >> 3;
    const int tid  = threadIdx.x;
    const int wave = tid >> 6;
    const int lane = tid & 63;
    const int quad = lane >> 4;
    const int l15  = lane & 15;
    const int q0w  = qt * 128 + wave * 32;

    __shared__ unsigned short Kt[32 * KS];
    __shared__ unsigned short VTl[64 * VTS];
    __shared__ unsigned short Pt[4][16 * PS];
    __shared__ float btl[2048];

    // [0,1024): poison (reached only when kk > qi in non-final tiles)
    // [1024,2048): bias * log2(e) for the exp2 path
    for (int i = tid; i < 2048; i += 256)
        btl[i] = (i < 1024) ? -1.0e9f : bt[1023 + i] * 1.442695041f;

    const float c2 = 0.125f * 1.442695041f;   // QK scale * log2(e)

    bf16x8 qa[2][2];
    const size_t qbase = ((size_t)(b * H_ + q0w)) * E_ + nh * HD_;
#pragma unroll
    for (int qf = 0; qf < 2; qf++)
#pragma unroll
        for (int ch = 0; ch < 2; ch++)
            qa[qf][ch] = *(const bf16x8*)(q + qbase + (size_t)(qf * 16 + l15) * E_ + ch * 32 + quad * 8);

    bf16x8 ones;
#pragma unroll
    for (int j = 0; j < 8; j++) ((short*)&ones)[j] = (short)0x3F80;

    f32x4 o[2][4] = {};
    f32x4 lf[2] = {};
    bf16x8 pa[2];

    const int srow = tid >> 3;
    const int scol = (tid & 7) * 8;
    const int frow = tid >> 2;
    const int fcol = (tid & 3) * 8;
    const unsigned short* kbase = k16 + (size_t)(b * S1_) * 512 + nh * HD_;
    const unsigned short* vrow = vT + ((size_t)(b * 512 + nh * HD_ + frow)) * SV;
    const int ntiles = 4 * qt + 5;
    // write col-block swizzle operands
    const int wblk0 = (l15 >> 3);        // + f*2, ^quad at use
    const int wsub  = (l15 & 7);
    const int rblk  = (quad ^ ((l15 >> 2) & 3)) << 3;

    // T14 prologue: load tile 0 into registers
    bf16x8 kreg = *(const bf16x8*)(kbase + (size_t)srow * 512 + scol);
    bf16x8 vreg = *(const bf16x8*)(vrow + fcol);

    for (int t = 0; t < ntiles; t++) {
        const int k0 = (t == ntiles - 1) ? 1024 : t * 32;
        __syncthreads();
        {
            *(bf16x8*)&Kt[srow * KS + scol] = kreg;
            *(bf16x8*)&VTl[frow * VTS + fcol] = vreg;
        }
        __syncthreads();
        // issue next tile's global loads; latency hides under compute below
        if (t + 1 < ntiles) {
            const int nk0 = (t + 1 == ntiles - 1) ? 1024 : (t + 1) * 32;
            kreg = *(const bf16x8*)(kbase + (size_t)(nk0 + srow) * 512 + scol);
            vreg = *(const bf16x8*)(vrow + nk0 + fcol);
        }

        f32x4 s[2][2] = {};
        __builtin_amdgcn_s_setprio(1);
#pragma unroll
        for (int ch = 0; ch < 2; ch++) {
            const bf16x8 kb0 = *(const bf16x8*)&Kt[l15 * KS + ch * 32 + quad * 8];
            const bf16x8 kb1 = *(const bf16x8*)&Kt[(16 + l15) * KS + ch * 32 + quad * 8];
            s[0][0] = __builtin_amdgcn_mfma_f32_16x16x32_bf16(qa[0][ch], kb0, s[0][0], 0, 0, 0);
            s[1][0] = __builtin_amdgcn_mfma_f32_16x16x32_bf16(qa[1][ch], kb0, s[1][0], 0, 0, 0);
            s[0][1] = __builtin_amdgcn_mfma_f32_16x16x32_bf16(qa[0][ch], kb1, s[0][1], 0, 0, 0);
            s[1][1] = __builtin_amdgcn_mfma_f32_16x16x32_bf16(qa[1][ch], kb1, s[1][1], 0, 0, 0);
        }
        __builtin_amdgcn_s_setprio(0);

        if (t != ntiles - 1) {
#pragma unroll
            for (int qf = 0; qf < 2; qf++) {
                unsigned short* pw = Pt[wave];
#pragma unroll
                for (int f = 0; f < 2; f++) {
                    const int base = q0w + qf * 16 + quad * 4 - (k0 + f * 16 + l15) + 1024;
                    const int cswz = ((f * 2 + wblk0) ^ quad) * 8 + wsub;
#pragma unroll
                    for (int r = 0; r < 4; r++) {
                        const float pp = EXP2F(s[qf][f][r] * c2 + btl[base + r]);
                        pw[(quad * 4 + r) * PS + cswz] = f2bf(pp);
                    }
                }
                pa[qf] = *(const bf16x8*)&pw[l15 * PS + rblk];
            }
        } else {
            // static-token tile: only kk==1024 visible; bias from global bt
#pragma unroll
            for (int qf = 0; qf < 2; qf++) {
                unsigned short* pw = Pt[wave];
#pragma unroll
                for (int f = 0; f < 2; f++) {
                    const int kk = k0 + f * 16 + l15;
                    const int cswz = ((f * 2 + wblk0) ^ quad) * 8 + wsub;
#pragma unroll
                    for (int r = 0; r < 4; r++) {
                        const int qi = q0w + qf * 16 + quad * 4 + r;
                        const float pp = (kk == 1024)
                            ? __expf(s[qf][f][r] * 0.125f + bt[1023 + qi]) : 0.f;
                        pw[(quad * 4 + r) * PS + cswz] = f2bf(pp);
                    }
                }
                pa[qf] = *(const bf16x8*)&pw[l15 * PS + rblk];
            }
        }

        __builtin_amdgcn_s_setprio(1);
#pragma unroll
        for (int qf = 0; qf < 2; qf++)
            lf[qf] = __builtin_amdgcn_mfma_f32_16x16x32_bf16(pa[qf], ones, lf[qf], 0, 0, 0);
#pragma unroll
        for (int dt = 0; dt < 4; dt++) {
            const bf16x8 vb = *(const bf16x8*)&VTl[(dt * 16 + l15) * VTS + quad * 8];
#pragma unroll
            for (int qf = 0; qf < 2; qf++)
                o[qf][dt] = __builtin_amdgcn_mfma_f32_16x16x32_bf16(pa[qf], vb, o[qf][dt], 0, 0, 0);
        }
        __builtin_amdgcn_s_setprio(0);
    }

#pragma unroll
    for (int qf = 0; qf < 2; qf++) {
        unsigned short* crow = ctx + ((size_t)(b * H_ + q0w + qf * 16 + quad * 4)) * E_ + nh * HD_ + l15;
#pragma unroll
        for (int r = 0; r < 4; r++) {
            const float inv = 1.f / lf[qf][r];
#pragma unroll
            for (int dt = 0; dt < 4; dt++)
                crow[(size_t)r * E_ + dt * 16] = f2bf(o[qf][dt][r] * inv);
        }
    }
}

extern "C" void kernel_launch(void* const* d_in, const int* in_sizes, int n_in,
                              void* d_out, int out_size, void* d_ws, size_t ws_size,
                              hipStream_t stream)
{
    (void)in_sizes; (void)n_in; (void)out_size; (void)ws_size;
    const float* x      = (const float*)d_in[0];
    const float* dyn    = (const float*)d_in[1];
    const float* statIn = (const float*)d_in[2];
    const float* dyn_W  = (const float*)d_in[3];
    const float* dyn_b  = (const float*)d_in[4];
    const float* stat_W = (const float*)d_in[5];
    const float* stat_b = (const float*)d_in[6];
    const float* fW1    = (const float*)d_in[7];
    const float* fb1    = (const float*)d_in[8];
    const float* fW2    = (const float*)d_in[9];
    const float* fb2    = (const float*)d_in[10];
    const float* q_W    = (const float*)d_in[11];
    const float* q_b    = (const float*)d_in[12];
    const float* ipW    = (const float*)d_in[13];
    const float* ipb    = (const float*)d_in[14];
    const float* out_W  = (const float*)d_in[15];
    const float* out_b  = (const float*)d_in[16];
    const float* ctx_W  = (const float*)d_in[17];
    const float* ctx_b  = (const float*)d_in[18];
    const float* bt     = (const float*)d_in[19];
    float* out = (float*)d_out;
    const float* ipbkv = ipb + E_;

    // ---- workspace layout, ~80.7 MB ----
    const size_t KV_ROWS = 16512;
    char* w = (char*)d_ws; size_t off = 0;
    unsigned short* k16   = (unsigned short*)(w + off); off += KV_ROWS * 512 * 2;
    unsigned short* vtmp  = (unsigned short*)(w + off); off += KV_ROWS * 512 * 2;
    unsigned short* dyn16 = (unsigned short*)(w + off); off += (size_t)16 * 512 * SV * 2;
    unsigned short* q16   = (unsigned short*)(w + off); off += (size_t)B_ * H_ * E_ * 2;
    unsigned short* xT16  = (unsigned short*)(w + off); off += (size_t)B_ * H_ * C_ * 2;
    unsigned short* st16    = (unsigned short*)(w + off); off += (size_t)128 * E_ * 2;
    unsigned short* Wkv216  = (unsigned short*)(w + off); off += (size_t)1024 * 512 * 2;
    unsigned short* ipWkv16 = (unsigned short*)(w + off); off += (size_t)1024 * 512 * 2;
    unsigned short* ipWq16  = (unsigned short*)(w + off); off += (size_t)512 * 512 * 2;
    unsigned short* ctxW16  = (unsigned short*)(w + off); off += (size_t)256 * 512 * 2;
    unsigned short* qWT16   = (unsigned short*)(w + off); off += (size_t)256 * 512 * 2;
    unsigned short* dynWT16 = (unsigned short*)(w + off); off += (size_t)512 * 512 * 2;
    unsigned short* outWT16 = (unsigned short*)(w + off); off += (size_t)512 * 512 * 2;
    unsigned short* WqW16   = (unsigned short*)(w + off); off += (size_t)E_ * C_ * 2;
    unsigned short* M216    = (unsigned short*)(w + off); off += (size_t)C_ * E_ * 2;
    float* scaleB = (float*)(w + off); off += (size_t)B_ * C_ * 4;
    float* qb2    = (float*)(w + off); off += E_ * 4;
    float* bkv2   = (float*)(w + off); off += 1024 * 4;
    float* cb2    = (float*)(w + off); off += C_ * 4;
    float* st_g   = (float*)(w + off); off += (size_t)B_ * E_ * 4;
    float* h1_g   = (float*)(w + off); off += (size_t)B_ * E_ * 4;
    unsigned short* vT16  = dyn16;   // dyn dead after KV GEMM
    unsigned short* ctx16 = vtmp;    // vtmp dead after vtrans

    // 1a. convs (grid-stride) + stat stage + x transpose
    prep_conv<<<1600, 512, 0, stream>>>(dyn, dyn16, ipW, ipWq16, ipWkv16, ctx_W, ctxW16,
                                        statIn, stat_W, stat_b, st_g, st16, x, xT16);
    // 1b. film1 + bias folds + weight transposes
    prep_misc<<<512, 512, 0, stream>>>(ipW, ipb, ctx_W, q_W, qWT16, dyn_W, dynWT16,
                                       out_W, outWT16, q_b, qb2, dyn_b, bkv2,
                                       out_b, ctx_b, cb2,
                                       st_g, fW1, fb1, h1_g);
    // 2. weight folds on MFMA + film2 stage
    gemm_fold3<<<112, 256, 0, stream>>>(ipWq16, qWT16, WqW16,
                                        ipWkv16, dynWT16, Wkv216,
                                        ctxW16, outWT16, M216,
                                        h1_g, fW2, fb2, scaleB);
    // 3. merged q + kv GEMMs, XCD-swizzled, pipelined
    gemm_qkv<<<1544, 256, 0, stream>>>(xT16, WqW16, qb2, q16,
                                       dyn16, st16, Wkv216, ipWkv16, bkv2, ipbkv,
                                       k16, vtmp);
    // 4. V transpose -> vT16
    vtrans_kernel<<<dim3(17, 8, B_), 256, 0, stream>>>(vtmp, vT16);
    // 5. flash attention -> ctx16
    attn_mfma_kernel<<<1024, 256, 0, stream>>>(q16, k16, vT16, bt, ctx16);
    // 6. final: 64x128 tiles, 512 blocks
    gemm_final<<<dim3(H_ / 128, C_ / 64, B_), 256, 0, stream>>>(
        M216, ctx16, cb2, out, x, scaleB);
}

// Round 15
// 260.446 us; speedup vs baseline: 1.0190x; 1.0190x over previous
//
#include <hip/hip_runtime.h>
#include <cmath>

#define B_  16
#define C_  256
#define H_  1024
#define S_  1024
#define E_  512
#define NH_ 8
#define DD_ 512
#define DS_ 64
#define HD_ 64
#define S1_ 1025
#define RELM 2048
#define SV  1032   // vT row stride (tokens), 16B-aligned

typedef __attribute__((ext_vector_type(8))) short bf16x8;
typedef __attribute__((ext_vector_type(4))) float f32x4;

__device__ __forceinline__ unsigned short f2bf(float f) {
    unsigned u = __float_as_uint(f);
    u += 0x7fffu + ((u >> 16) & 1u);   // RNE
    return (unsigned short)(u >> 16);
}

#if __has_builtin(__builtin_amdgcn_exp2f)
#define EXP2F(x) __builtin_amdgcn_exp2f(x)
#else
#define EXP2F(x) exp2f(x)
#endif

// async global->LDS, 16B per lane (m97 pattern)
__device__ __forceinline__ void gl2lds16(const unsigned short* g, unsigned short* l) {
#if __has_builtin(__builtin_amdgcn_global_load_lds)
    __builtin_amdgcn_global_load_lds(
        (const __attribute__((address_space(1))) void*)g,
        (__attribute__((address_space(3))) void*)l, 16, 0, 0);
#else
    const int ln = threadIdx.x & 63;
    *(bf16x8*)(l + ln * 8) = *(const bf16x8*)g;
#endif
}

__device__ __forceinline__ void conv8(const float* __restrict__ src,
                                      unsigned short* __restrict__ dst, int i) {
    float4 a = *(const float4*)(src + i);
    float4 b = *(const float4*)(src + i + 4);
    bf16x8 o;
    ((unsigned short*)&o)[0] = f2bf(a.x); ((unsigned short*)&o)[1] = f2bf(a.y);
    ((unsigned short*)&o)[2] = f2bf(a.z); ((unsigned short*)&o)[3] = f2bf(a.w);
    ((unsigned short*)&o)[4] = f2bf(b.x); ((unsigned short*)&o)[5] = f2bf(b.y);
    ((unsigned short*)&o)[6] = f2bf(b.z); ((unsigned short*)&o)[7] = f2bf(b.w);
    *(bf16x8*)(dst + i) = o;
}

// 64-lane butterfly sum
__device__ __forceinline__ float wred(float p) {
#pragma unroll
    for (int off = 32; off; off >>= 1) p += __shfl_down(p, off, 64);
    return p;
}

// ---- launch 1: all input-only prep ----
// [0,512): conv grid-stride | [512,576): stat | [576,1600): xpose
// [1600,1824): rowdots | [1824,1984): weight transposes
#define U_DYN 1048576
#define U_KV  1114112
#define U_Q   1146880
#define U_TOT 1163264
__global__ __launch_bounds__(512)
void prep_conv(const float* __restrict__ dyn, unsigned short* __restrict__ dyn16,
               const float* __restrict__ ipW, const float* __restrict__ ipb,
               unsigned short* __restrict__ ipWq16, unsigned short* __restrict__ ipWkv16,
               const float* __restrict__ ctxW, unsigned short* __restrict__ ctxW16,
               const float* __restrict__ statIn,
               const float* __restrict__ stat_W, const float* __restrict__ stat_b,
               float* __restrict__ st_g, unsigned short* __restrict__ st16,
               const float* __restrict__ x, unsigned short* __restrict__ xT,
               const float* __restrict__ q_W, unsigned short* __restrict__ qWT16,
               const float* __restrict__ dynW, unsigned short* __restrict__ dynWT16,
               const float* __restrict__ outW, unsigned short* __restrict__ outWT16,
               const float* __restrict__ q_b, float* __restrict__ qb2,
               const float* __restrict__ dyn_b, float* __restrict__ bkv2,
               const float* __restrict__ out_b, const float* __restrict__ ctx_b,
               float* __restrict__ cb2)
{
    __shared__ float tle[64][65];
    const int blk = blockIdx.x;
    const int t = threadIdx.x;
    const float* ipWkv = ipW + (size_t)E_ * E_;
    const float* ipbkv = ipb + E_;
    if (blk < 512) {
        const int stride = 512 * 512;
        for (int u = blk * 512 + t; u < U_TOT; u += stride) {
            if (u < U_DYN)      conv8(dyn,   dyn16,   u * 8);
            else if (u < U_KV)  conv8(ipWkv, ipWkv16, (u - U_DYN) * 8);
            else if (u < U_Q)   conv8(ipW,   ipWq16,  (u - U_KV) * 8);
            else                conv8(ctxW,  ctxW16,  (u - U_Q) * 8);
        }
    } else if (blk < 576) {
        // stat[b][r] = stat_b[r] + statIn[b] . stat_W[r]  (K=64 = one elem/lane)
        const int sub = blk - 512;
        const int b = sub >> 2;
        const int q = sub & 3;          // row quarter (128 rows)
        const int wv = t >> 6;
        const int ln = t & 63;
        const float sv = statIn[b * DS_ + ln];
#pragma unroll 4
        for (int i = 0; i < 16; i++) {
            const int r = q * 128 + wv * 16 + i;
            const float p = wred(stat_W[(size_t)r * DS_ + ln] * sv);
            if (ln == 0) {
                const float v = p + stat_b[r];
                st_g[(size_t)b * E_ + r] = v;
                st16[(size_t)b * E_ + r] = f2bf(v);
            }
        }
    } else if (blk < 1600) {
        // xT[b*H + h][c] = bf16(x[b][c][h]) — 64x64 tile, 512 threads
        const int sub = blk - 576;
        const int b  = sub >> 6;
        const int c0 = ((sub >> 4) & 3) * 64;
        const int h0 = (sub & 15) * 64;
        const int tx = t & 15, ty = t >> 4;          // ty in [0,32)
#pragma unroll
        for (int i = 0; i < 2; i++) {
            const float4 v = *(const float4*)&x[((size_t)(b * C_ + c0 + ty + i * 32)) * H_ + h0 + tx * 4];
            tle[ty + i * 32][tx * 4 + 0] = v.x;
            tle[ty + i * 32][tx * 4 + 1] = v.y;
            tle[ty + i * 32][tx * 4 + 2] = v.z;
            tle[ty + i * 32][tx * 4 + 3] = v.w;
        }
        __syncthreads();
#pragma unroll
        for (int i = 0; i < 2; i++) {
            const int hh = ty + i * 32;
            ushort4 o;
            o.x = f2bf(tle[tx * 4 + 0][hh]);
            o.y = f2bf(tle[tx * 4 + 1][hh]);
            o.z = f2bf(tle[tx * 4 + 2][hh]);
            o.w = f2bf(tle[tx * 4 + 3][hh]);
            *(ushort4*)&xT[((size_t)(b * H_ + h0 + hh)) * C_ + c0 + tx * 4] = o;
        }
    } else if (blk < 1824) {
        // ---- bias-fold row dots: qb2 (512) | bkv2 (1024) | cb2 (256) ----
        const int row = (blk - 1600) * 8 + (t >> 6);
        const int ln  = t & 63;
        const float* src; const float* vec; float bias; float* dst;
        if (row < 512)       { src = ipW + (size_t)row * E_;            vec = q_b;   bias = ipb[row];        dst = qb2 + row; }
        else if (row < 1536) { const int n = row - 512;  src = ipWkv + (size_t)n * E_; vec = dyn_b; bias = ipbkv[n]; dst = bkv2 + n; }
        else                 { const int n = row - 1536; src = ctxW + (size_t)n * E_;  vec = out_b; bias = ctx_b[n]; dst = cb2 + n; }
        const float4 a  = *(const float4*)(src + ln * 8);
        const float4 c  = *(const float4*)(src + ln * 8 + 4);
        const float4 va = *(const float4*)(vec + ln * 8);
        const float4 vc = *(const float4*)(vec + ln * 8 + 4);
        float p = a.x * va.x + a.y * va.y + a.z * va.z + a.w * va.w
                + c.x * vc.x + c.y * vc.y + c.z * vc.z + c.w * vc.w;
        p = wred(p);
        if (ln == 0) *dst = p + bias;
    } else {
        // transpose fp32 (R x Cc) -> bf16 (Cc x R)
        const float* src; unsigned short* dst; int R, Cc, tile;
        const int tt = blk - 1824;
        if (tt < 32)      { src = q_W;  dst = qWT16;   R = 512; Cc = 256; tile = tt; }
        else if (tt < 96) { src = dynW; dst = dynWT16; R = 512; Cc = 512; tile = tt - 32; }
        else              { src = outW; dst = outWT16; R = 512; Cc = 512; tile = tt - 96; }
        const int tpr = Cc / 64;                    // tiles per row-band
        const int r0 = (tile / tpr) * 64;
        const int c0 = (tile % tpr) * 64;
        const int tx = t & 15, ty = t >> 4;         // ty in [0,32)
#pragma unroll
        for (int i = 0; i < 2; i++) {
            const float4 v = *(const float4*)&src[(size_t)(r0 + ty + i * 32) * Cc + c0 + tx * 4];
            tle[ty + i * 32][tx * 4 + 0] = v.x;
            tle[ty + i * 32][tx * 4 + 1] = v.y;
            tle[ty + i * 32][tx * 4 + 2] = v.z;
            tle[ty + i * 32][tx * 4 + 3] = v.w;
        }
        __syncthreads();
#pragma unroll
        for (int i = 0; i < 2; i++) {
            const int cc = ty + i * 32;
            ushort4 o;
            o.x = f2bf(tle[tx * 4 + 0][cc]);
            o.y = f2bf(tle[tx * 4 + 1][cc]);
            o.z = f2bf(tle[tx * 4 + 2][cc]);
            o.w = f2bf(tle[tx * 4 + 3][cc]);
            *(ushort4*)&dst[(size_t)(c0 + cc) * R + r0 + tx * 4] = o;
        }
    }
}

// ---- launch 2: three weight-fold GEMMs + film1 (blocks [48,176)) ----
// [0,8): WqW 512x256 | [8,40): Wkv2 1024x512 | [40,48): M2 256x512 | [48,176): film1
__global__ __launch_bounds__(256)
void gemm_fold3(const unsigned short* __restrict__ ipWq16, const unsigned short* __restrict__ qWT16,
                unsigned short* __restrict__ WqW16,
                const unsigned short* __restrict__ ipWkv16, const unsigned short* __restrict__ dynWT16,
                unsigned short* __restrict__ Wkv216,
                const unsigned short* __restrict__ ctxW16, const unsigned short* __restrict__ outWT16,
                unsigned short* __restrict__ M216,
                const float* __restrict__ st_g,
                const float* __restrict__ fW1, const float* __restrict__ fb1,
                float* __restrict__ h1_g)
{
    __shared__ unsigned short At[128 * 32];
    __shared__ unsigned short Wt[128 * 32];
    const int bid = blockIdx.x;
    const int tid  = threadIdx.x;
    if (bid >= 48) {
        // ---- film1: h1[b][r] = leaky(fb1[r] + st[b] . fW1[r]), K=512 ----
        const int sub = bid - 48;
        const int b   = sub >> 3;
        const int oct = sub & 7;        // 64-row slice
        const int wv  = tid >> 6;       // 4 waves
        const int ln  = tid & 63;
        float str[8];
        *(float4*)&str[0] = *(const float4*)&st_g[(size_t)b * E_ + ln * 8];
        *(float4*)&str[4] = *(const float4*)&st_g[(size_t)b * E_ + ln * 8 + 4];
#pragma unroll 2
        for (int i = 0; i < 16; i++) {
            const int r = oct * 64 + wv * 16 + i;
            const float* wr = fW1 + (size_t)r * E_ + ln * 8;
            const float4 a = *(const float4*)wr;
            const float4 c = *(const float4*)(wr + 4);
            float p = a.x * str[0] + a.y * str[1] + a.z * str[2] + a.w * str[3]
                    + c.x * str[4] + c.y * str[5] + c.z * str[6] + c.w * str[7];
            p = wred(p);
            if (ln == 0) {
                const float v = p + fb1[r];
                h1_g[(size_t)b * E_ + r] = (v >= 0.f) ? v : 0.1f * v;
            }
        }
        return;
    }
    const unsigned short *A, *W; unsigned short* O; int N, mb, nb;
    if (bid < 8)       { A = ipWq16;  W = qWT16;   O = WqW16;  N = 256; mb = bid >> 1;       nb = bid & 1; }
    else if (bid < 40) { A = ipWkv16; W = dynWT16; O = Wkv216; N = 512; mb = (bid - 8) >> 2; nb = (bid - 8) & 3; }
    else               { A = ctxW16;  W = outWT16; O = M216;   N = 512; mb = (bid - 40) >> 2; nb = (bid - 40) & 3; }
    const int m0 = mb * 128, n0 = nb * 128;

    const int wave = tid >> 6;
    const int lane = tid & 63;
    const int quad = lane >> 4;
    const int l15  = lane & 15;
    const int rw = (wave >> 1) * 64;
    const int cw = (wave & 1) * 64;
    const int srow = lane >> 2;
    const int scol = (lane & 3) * 8;

    f32x4 acc[4][4] = {};
    for (int k0 = 0; k0 < 512; k0 += 32) {
        __syncthreads();
#pragma unroll
        for (int c = 0; c < 2; c++) {
            const int chunk = wave + c * 4;
            gl2lds16(A + (size_t)(m0 + chunk * 16 + srow) * 512 + k0 + scol, &At[chunk * 512]);
            gl2lds16(W + (size_t)(n0 + chunk * 16 + srow) * 512 + k0 + scol, &Wt[chunk * 512]);
        }
        __syncthreads();
        bf16x8 af[4], wf[4];
#pragma unroll
        for (int i = 0; i < 4; i++)
            af[i] = *(const bf16x8*)&At[(rw + i * 16 + l15) * 32 + quad * 8];
#pragma unroll
        for (int j = 0; j < 4; j++)
            wf[j] = *(const bf16x8*)&Wt[(cw + j * 16 + l15) * 32 + quad * 8];
#pragma unroll
        for (int i = 0; i < 4; i++)
#pragma unroll
            for (int j = 0; j < 4; j++)
                acc[i][j] = __builtin_amdgcn_mfma_f32_16x16x32_bf16(af[i], wf[j], acc[i][j], 0, 0, 0);
    }
#pragma unroll
    for (int i = 0; i < 4; i++)
#pragma unroll
        for (int r = 0; r < 4; r++) {
            const int mm = m0 + rw + i * 16 + quad * 4 + r;
            unsigned short* cp = O + (size_t)mm * N + n0 + cw + l15;
#pragma unroll
            for (int j = 0; j < 4; j++)
                cp[j * 16] = f2bf(acc[i][j][r]);
        }
}

// ---- launch 3: merged Q + KV GEMMs (2-phase pipelined, XCD-swizzled) + film2 ----
// bid<1544: GEMM tiles; bid>=1544: film2 (64 blocks)
__global__ __launch_bounds__(256)
void gemm_qkv(const unsigned short* __restrict__ xT16, const unsigned short* __restrict__ WqW16,
              const float* __restrict__ qb2, unsigned short* __restrict__ q16,
              const unsigned short* __restrict__ dynA, const unsigned short* __restrict__ stA,
              const unsigned short* __restrict__ Wdyn, const unsigned short* __restrict__ Wst,
              const float* __restrict__ bdyn, const float* __restrict__ bst,
              unsigned short* __restrict__ k16, unsigned short* __restrict__ vtmp,
              const float* __restrict__ h1_g,
              const float* __restrict__ fW2, const float* __restrict__ fb2,
              float* __restrict__ scaleB)
{
    __shared__ unsigned short At[2][128 * 32];
    __shared__ unsigned short Wt[2][128 * 32];
    const int bid0 = blockIdx.x;
    const int tid  = threadIdx.x;
    if (bid0 >= 1544) {
        // ---- film2: scaleB[b][c] = 1 + tanh(fb2[c] + h1[b] . fW2[c]), K=512 ----
        const int sub = bid0 - 1544;
        const int b = sub >> 2;
        const int q = sub & 3;          // 64-row slice
        const int wv = tid >> 6;        // 4 waves
        const int ln = tid & 63;
        float h1r[8];
        *(float4*)&h1r[0] = *(const float4*)&h1_g[(size_t)b * E_ + ln * 8];
        *(float4*)&h1r[4] = *(const float4*)&h1_g[(size_t)b * E_ + ln * 8 + 4];
#pragma unroll 2
        for (int i = 0; i < 16; i++) {
            const int c = q * 64 + wv * 16 + i;
            const float* wr = fW2 + (size_t)c * E_ + ln * 8;
            const float4 a = *(const float4*)wr;
            const float4 cc = *(const float4*)(wr + 4);
            float p = a.x * h1r[0] + a.y * h1r[1] + a.z * h1r[2] + a.w * h1r[3]
                    + cc.x * h1r[4] + cc.y * h1r[5] + cc.z * h1r[6] + cc.w * h1r[7];
            p = wred(p);
            if (ln == 0) scaleB[b * C_ + c] = 1.f + tanhf(p + fb2[c]);
        }
        return;
    }
    const int t = (bid0 & 7) * 193 + (bid0 >> 3);   // XCD-contiguous logical band

    const int wave = tid >> 6;
    const int lane = tid & 63;
    const int quad = lane >> 4;
    const int l15  = lane & 15;
    const int rw = (wave >> 1) * 64;
    const int cw = (wave & 1) * 64;
    const int srow = lane >> 2;
    const int scol = (lane & 3) * 8;

    const unsigned short *A, *W;
    int m0, n0, K;
    bool isQ, stat = false;
    if (t < 1032) {
        const int y = t >> 3;
        stat = (y == 128);
        A = stat ? stA : dynA;
        W = stat ? Wst : Wdyn;
        m0 = stat ? 0 : y * 128;
        n0 = (t & 7) * 128;
        K = 512; isQ = false;
    } else {
        const int u = t - 1032;
        A = xT16; W = WqW16;
        m0 = (u >> 2) * 128;
        n0 = (u & 3) * 128;
        K = 256; isQ = true;
    }

    f32x4 acc[4][4] = {};
    // prologue: stage k0=0 into buffer 0
#pragma unroll
    for (int c = 0; c < 2; c++) {
        const int chunk = wave + c * 4;
        gl2lds16(A + (size_t)(m0 + chunk * 16 + srow) * K + scol, &At[0][chunk * 512]);
        gl2lds16(W + (size_t)(n0 + chunk * 16 + srow) * K + scol, &Wt[0][chunk * 512]);
    }
    int cur = 0;
    for (int k0 = 0; k0 < K; k0 += 32) {
        __syncthreads();               // stage(cur) complete
        if (k0 + 32 < K) {
            const int kn = k0 + 32;
#pragma unroll
            for (int c = 0; c < 2; c++) {
                const int chunk = wave + c * 4;
                gl2lds16(A + (size_t)(m0 + chunk * 16 + srow) * K + kn + scol, &At[cur ^ 1][chunk * 512]);
                gl2lds16(W + (size_t)(n0 + chunk * 16 + srow) * K + kn + scol, &Wt[cur ^ 1][chunk * 512]);
            }
        }
        bf16x8 af[4], wf[4];
#pragma unroll
        for (int i = 0; i < 4; i++)
            af[i] = *(const bf16x8*)&At[cur][(rw + i * 16 + l15) * 32 + quad * 8];
#pragma unroll
        for (int j = 0; j < 4; j++)
            wf[j] = *(const bf16x8*)&Wt[cur][(cw + j * 16 + l15) * 32 + quad * 8];
#pragma unroll
        for (int i = 0; i < 4; i++)
#pragma unroll
            for (int j = 0; j < 4; j++)
                acc[i][j] = __builtin_amdgcn_mfma_f32_16x16x32_bf16(af[i], wf[j], acc[i][j], 0, 0, 0);
        cur ^= 1;
    }

    if (isQ) {
        float bias4[4];
#pragma unroll
        for (int j = 0; j < 4; j++) bias4[j] = qb2[n0 + cw + j * 16 + l15];
#pragma unroll
        for (int i = 0; i < 4; i++) {
#pragma unroll
            for (int r = 0; r < 4; r++) {
                const int mm = m0 + rw + i * 16 + quad * 4 + r;
                unsigned short* cp = q16 + (size_t)mm * 512 + n0 + cw + l15;
#pragma unroll
                for (int j = 0; j < 4; j++)
                    cp[j * 16] = f2bf(acc[i][j][r] + bias4[j]);
            }
        }
    } else {
        const float* bias = stat ? bst : bdyn;
        const bool isV = (n0 >= 512);
        unsigned short* base = isV ? vtmp : k16;
        const int c0 = (isV ? n0 - 512 : n0) + cw + l15;
        float bias4[4];
#pragma unroll
        for (int j = 0; j < 4; j++) bias4[j] = bias[n0 + cw + j * 16 + l15];
#pragma unroll
        for (int i = 0; i < 4; i++) {
#pragma unroll
            for (int r = 0; r < 4; r++) {
                const int am = m0 + rw + i * 16 + quad * 4 + r;
                if (!stat || am < 16) {
                    const int orow = stat ? (am * S1_ + S_) : ((am >> 10) * S1_ + (am & 1023));
                    unsigned short* cp = base + (size_t)orow * 512 + c0;
#pragma unroll
                    for (int j = 0; j < 4; j++)
                        cp[j * 16] = f2bf(acc[i][j][r] + bias4[j]);
                }
            }
        }
    }
}

// ---- final GEMM (residual + FiLM scale), 64x128 tiles -> 512 blocks ----
__global__ __launch_bounds__(256)
void gemm_final(const unsigned short* __restrict__ A, const unsigned short* __restrict__ W,
                const float* __restrict__ bias, float* __restrict__ Cout,
                const float* __restrict__ x, const float* __restrict__ scale)
{
    __shared__ unsigned short At[64 * 32];
    __shared__ unsigned short Wt[128 * 32];
    const int tid  = threadIdx.x;
    const int wave = tid >> 6;
    const int lane = tid & 63;
    const int quad = lane >> 4;
    const int l15  = lane & 15;
    const int m0 = blockIdx.y * 64;     // C rows
    const int n0 = blockIdx.x * 128;    // H cols
    const int rw = (wave >> 1) * 32;
    const int cw = (wave & 1) * 64;
    const int zb = blockIdx.z;
    const unsigned short* Wb = W + (size_t)zb * H_ * E_;

    const int srow = lane >> 2;
    const int scol = (lane & 3) * 8;

    f32x4 acc[2][4] = {};

    for (int k0 = 0; k0 < E_; k0 += 32) {
        __syncthreads();
        gl2lds16(A  + (size_t)(m0 + wave * 16 + srow) * E_ + k0 + scol, &At[wave * 512]);
#pragma unroll
        for (int c = 0; c < 2; c++) {
            const int chunk = wave + c * 4;
            gl2lds16(Wb + (size_t)(n0 + chunk * 16 + srow) * E_ + k0 + scol, &Wt[chunk * 512]);
        }
        __syncthreads();
        bf16x8 af[2], wf[4];
#pragma unroll
        for (int i = 0; i < 2; i++)
            af[i] = *(const bf16x8*)&At[(rw + i * 16 + l15) * 32 + quad * 8];
#pragma unroll
        for (int j = 0; j < 4; j++)
            wf[j] = *(const bf16x8*)&Wt[(cw + j * 16 + l15) * 32 + quad * 8];
#pragma unroll
        for (int i = 0; i < 2; i++)
#pragma unroll
            for (int j = 0; j < 4; j++)
                acc[i][j] = __builtin_amdgcn_mfma_f32_16x16x32_bf16(af[i], wf[j], acc[i][j], 0, 0, 0);
    }

#pragma unroll
    for (int i = 0; i < 2; i++) {
#pragma unroll
        for (int r = 0; r < 4; r++) {
            const int mm = m0 + rw + i * 16 + quad * 4 + r;
            const float cb = bias[mm];
            const float sc = scale[zb * C_ + mm];
            const size_t base = ((size_t)(zb * C_ + mm)) * H_ + n0 + cw + l15;
#pragma unroll
            for (int j = 0; j < 4; j++)
                Cout[base + j * 16] = (x[base + j * 16] + acc[i][j][r] + cb) * sc;
        }
    }
}

// vT[b][d][s] = vtmp[b*1025+s][d], row stride SV, zero-fill s>=1025
__global__ __launch_bounds__(256)
void vtrans_kernel(const unsigned short* __restrict__ vtmp, unsigned short* __restrict__ vT)
{
    __shared__ unsigned short tle[64][72];
    const int b = blockIdx.z;
    const int s0 = blockIdx.x * 64;
    const int d0 = blockIdx.y * 64;
    const int tx = threadIdx.x & 15;
    const int ty = threadIdx.x >> 4;
#pragma unroll
    for (int i = 0; i < 4; i++) {
        const int s = s0 + ty + i * 16;
        ushort4 v = {0, 0, 0, 0};
        if (s < S1_)
            v = *(const ushort4*)&vtmp[((size_t)(b * S1_ + s)) * 512 + d0 + tx * 4];
        tle[ty + i * 16][tx * 4 + 0] = v.x;
        tle[ty + i * 16][tx * 4 + 1] = v.y;
        tle[ty + i * 16][tx * 4 + 2] = v.z;
        tle[ty + i * 16][tx * 4 + 3] = v.w;
    }
    __syncthreads();
    if (s0 + tx * 4 < SV) {
#pragma unroll
        for (int i = 0; i < 4; i++) {
            const int dd = ty + i * 16;
            ushort4 o;
            o.x = tle[tx * 4 + 0][dd];
            o.y = tle[tx * 4 + 1][dd];
            o.z = tle[tx * 4 + 2][dd];
            o.w = tle[tx * 4 + 3][dd];
            *(ushort4*)&vT[((size_t)(b * 512 + d0 + dd)) * SV + s0 + tx * 4] = o;
        }
    }
}

// ---- MFMA flash attention, Q-tile 128, 32-key tiles, pre-transposed V ----
// T14 async-stage; poison bias + exp2; XOR-swizzled Pt; T5 setprio.
#define KS 72
#define VTS 40
#define PS 40

__global__ __launch_bounds__(256)
void attn_mfma_kernel(const unsigned short* __restrict__ q,
                      const unsigned short* __restrict__ k16,
                      const unsigned short* __restrict__ vT,
                      const float* __restrict__ bt,
                      unsigned short* __restrict__ ctx)
{
    const int blk  = blockIdx.x;
    const int qt   = 7 - (blk >> 7);
    const int pair = blk & 127;
    const int nh   = pair & 7;
    const int b    = pair >> 3;
    const int tid  = threadIdx.x;
    const int wave = tid >> 6;
    const int lane = tid & 63;
    const int quad = lane >> 4;
    const int l15  = lane & 15;
    const int q0w  = qt * 128 + wave * 32;

    __shared__ unsigned short Kt[32 * KS];
    __shared__ unsigned short VTl[64 * VTS];
    __shared__ unsigned short Pt[4][16 * PS];
    __shared__ float btl[2048];

    for (int i = tid; i < 2048; i += 256)
        btl[i] = (i < 1024) ? -1.0e9f : bt[1023 + i] * 1.442695041f;

    const float c2 = 0.125f * 1.442695041f;   // QK scale * log2(e)

    bf16x8 qa[2][2];
    const size_t qbase = ((size_t)(b * H_ + q0w)) * E_ + nh * HD_;
#pragma unroll
    for (int qf = 0; qf < 2; qf++)
#pragma unroll
        for (int ch = 0; ch < 2; ch++)
            qa[qf][ch] = *(const bf16x8*)(q + qbase + (size_t)(qf * 16 + l15) * E_ + ch * 32 + quad * 8);

    bf16x8 ones;
#pragma unroll
    for (int j = 0; j < 8; j++) ((short*)&ones)[j] = (short)0x3F80;

    f32x4 o[2][4] = {};
    f32x4 lf[2] = {};
    bf16x8 pa[2];

    const int srow = tid >> 3;
    const int scol = (tid & 7) * 8;
    const int frow = tid >> 2;
    const int fcol = (tid & 3) * 8;
    const unsigned short* kbase = k16 + (size_t)(b * S1_) * 512 + nh * HD_;
    const unsigned short* vrow = vT + ((size_t)(b * 512 + nh * HD_ + frow)) * SV;
    const int ntiles = 4 * qt + 5;
    const int wblk0 = (l15 >> 3);
    const int wsub  = (l15 & 7);
    const int rblk  = (quad ^ ((l15 >> 2) & 3)) << 3;

    bf16x8 kreg = *(const bf16x8*)(kbase + (size_t)srow * 512 + scol);
    bf16x8 vreg = *(const bf16x8*)(vrow + fcol);

    for (int t = 0; t < ntiles; t++) {
        const int k0 = (t == ntiles - 1) ? 1024 : t * 32;
        __syncthreads();
        {
            *(bf16x8*)&Kt[srow * KS + scol] = kreg;
            *(bf16x8*)&VTl[frow * VTS + fcol] = vreg;
        }
        __syncthreads();
        if (t + 1 < ntiles) {
            const int nk0 = (t + 1 == ntiles - 1) ? 1024 : (t + 1) * 32;
            kreg = *(const bf16x8*)(kbase + (size_t)(nk0 + srow) * 512 + scol);
            vreg = *(const bf16x8*)(vrow + nk0 + fcol);
        }

        f32x4 s[2][2] = {};
        __builtin_amdgcn_s_setprio(1);
#pragma unroll
        for (int ch = 0; ch < 2; ch++) {
            const bf16x8 kb0 = *(const bf16x8*)&Kt[l15 * KS + ch * 32 + quad * 8];
            const bf16x8 kb1 = *(const bf16x8*)&Kt[(16 + l15) * KS + ch * 32 + quad * 8];
            s[0][0] = __builtin_amdgcn_mfma_f32_16x16x32_bf16(qa[0][ch], kb0, s[0][0], 0, 0, 0);
            s[1][0] = __builtin_amdgcn_mfma_f32_16x16x32_bf16(qa[1][ch], kb0, s[1][0], 0, 0, 0);
            s[0][1] = __builtin_amdgcn_mfma_f32_16x16x32_bf16(qa[0][ch], kb1, s[0][1], 0, 0, 0);
            s[1][1] = __builtin_amdgcn_mfma_f32_16x16x32_bf16(qa[1][ch], kb1, s[1][1], 0, 0, 0);
        }
        __builtin_amdgcn_s_setprio(0);

        if (t != ntiles - 1) {
#pragma unroll
            for (int qf = 0; qf < 2; qf++) {
                unsigned short* pw = Pt[wave];
#pragma unroll
                for (int f = 0; f < 2; f++) {
                    const int base = q0w + qf * 16 + quad * 4 - (k0 + f * 16 + l15) + 1024;
                    const int cswz = ((f * 2 + wblk0) ^ quad) * 8 + wsub;
#pragma unroll
                    for (int r = 0; r < 4; r++) {
                        const float pp = EXP2F(s[qf][f][r] * c2 + btl[base + r]);
                        pw[(quad * 4 + r) * PS + cswz] = f2bf(pp);
                    }
                }
                pa[qf] = *(const bf16x8*)&pw[l15 * PS + rblk];
            }
        } else {
#pragma unroll
            for (int qf = 0; qf < 2; qf++) {
                unsigned short* pw = Pt[wave];
#pragma unroll
                for (int f = 0; f < 2; f++) {
                    const int kk = k0 + f * 16 + l15;
                    const int cswz = ((f * 2 + wblk0) ^ quad) * 8 + wsub;
#pragma unroll
                    for (int r = 0; r < 4; r++) {
                        const int qi = q0w + qf * 16 + quad * 4 + r;
                        const float pp = (kk == 1024)
                            ? __expf(s[qf][f][r] * 0.125f + bt[1023 + qi]) : 0.f;
                        pw[(quad * 4 + r) * PS + cswz] = f2bf(pp);
                    }
                }
                pa[qf] = *(const bf16x8*)&pw[l15 * PS + rblk];
            }
        }

        __builtin_amdgcn_s_setprio(1);
#pragma unroll
        for (int qf = 0; qf < 2; qf++)
            lf[qf] = __builtin_amdgcn_mfma_f32_16x16x32_bf16(pa[qf], ones, lf[qf], 0, 0, 0);
#pragma unroll
        for (int dt = 0; dt < 4; dt++) {
            const bf16x8 vb = *(const bf16x8*)&VTl[(dt * 16 + l15) * VTS + quad * 8];
#pragma unroll
            for (int qf = 0; qf < 2; qf++)
                o[qf][dt] = __builtin_amdgcn_mfma_f32_16x16x32_bf16(pa[qf], vb, o[qf][dt], 0, 0, 0);
        }
        __builtin_amdgcn_s_setprio(0);
    }

#pragma unroll
    for (int qf = 0; qf < 2; qf++) {
        unsigned short* crow = ctx + ((size_t)(b * H_ + q0w + qf * 16 + quad * 4)) * E_ + nh * HD_ + l15;
#pragma unroll
        for (int r = 0; r < 4; r++) {
            const float inv = 1.f / lf[qf][r];
#pragma unroll
            for (int dt = 0; dt < 4; dt++)
                crow[(size_t)r * E_ + dt * 16] = f2bf(o[qf][dt][r] * inv);
        }
    }
}

extern "C" void kernel_launch(void* const* d_in, const int* in_sizes, int n_in,
                              void* d_out, int out_size, void* d_ws, size_t ws_size,
                              hipStream_t stream)
{
    (void)in_sizes; (void)n_in; (void)out_size; (void)ws_size;
    const float* x      = (const float*)d_in[0];
    const float* dyn    = (const float*)d_in[1];
    const float* statIn = (const float*)d_in[2];
    const float* dyn_W  = (const float*)d_in[3];
    const float* dyn_b  = (const float*)d_in[4];
    const float* stat_W = (const float*)d_in[5];
    const float* stat_b = (const float*)d_in[6];
    const float* fW1    = (const float*)d_in[7];
    const float* fb1    = (const float*)d_in[8];
    const float* fW2    = (const float*)d_in[9];
    const float* fb2    = (const float*)d_in[10];
    const float* q_W    = (const float*)d_in[11];
    const float* q_b    = (const float*)d_in[12];
    const float* ipW    = (const float*)d_in[13];
    const float* ipb    = (const float*)d_in[14];
    const float* out_W  = (const float*)d_in[15];
    const float* out_b  = (const float*)d_in[16];
    const float* ctx_W  = (const float*)d_in[17];
    const float* ctx_b  = (const float*)d_in[18];
    const float* bt     = (const float*)d_in[19];
    float* out = (float*)d_out;
    const float* ipbkv = ipb + E_;

    // ---- workspace layout, ~80.7 MB ----
    const size_t KV_ROWS = 16512;
    char* w = (char*)d_ws; size_t off = 0;
    unsigned short* k16   = (unsigned short*)(w + off); off += KV_ROWS * 512 * 2;
    unsigned short* vtmp  = (unsigned short*)(w + off); off += KV_ROWS * 512 * 2;
    unsigned short* dyn16 = (unsigned short*)(w + off); off += (size_t)16 * 512 * SV * 2;
    unsigned short* q16   = (unsigned short*)(w + off); off += (size_t)B_ * H_ * E_ * 2;
    unsigned short* xT16  = (unsigned short*)(w + off); off += (size_t)B_ * H_ * C_ * 2;
    unsigned short* st16    = (unsigned short*)(w + off); off += (size_t)128 * E_ * 2;
    unsigned short* Wkv216  = (unsigned short*)(w + off); off += (size_t)1024 * 512 * 2;
    unsigned short* ipWkv16 = (unsigned short*)(w + off); off += (size_t)1024 * 512 * 2;
    unsigned short* ipWq16  = (unsigned short*)(w + off); off += (size_t)512 * 512 * 2;
    unsigned short* ctxW16  = (unsigned short*)(w + off); off += (size_t)256 * 512 * 2;
    unsigned short* qWT16   = (unsigned short*)(w + off); off += (size_t)256 * 512 * 2;
    unsigned short* dynWT16 = (unsigned short*)(w + off); off += (size_t)512 * 512 * 2;
    unsigned short* outWT16 = (unsigned short*)(w + off); off += (size_t)512 * 512 * 2;
    unsigned short* WqW16   = (unsigned short*)(w + off); off += (size_t)E_ * C_ * 2;
    unsigned short* M216    = (unsigned short*)(w + off); off += (size_t)C_ * E_ * 2;
    float* scaleB = (float*)(w + off); off += (size_t)B_ * C_ * 4;
    float* qb2    = (float*)(w + off); off += E_ * 4;
    float* bkv2   = (float*)(w + off); off += 1024 * 4;
    float* cb2    = (float*)(w + off); off += C_ * 4;
    float* st_g   = (float*)(w + off); off += (size_t)B_ * E_ * 4;
    float* h1_g   = (float*)(w + off); off += (size_t)B_ * E_ * 4;
    unsigned short* vT16  = dyn16;   // dyn dead after KV GEMM
    unsigned short* ctx16 = vtmp;    // vtmp dead after vtrans

    // 1. all input-only prep: convs + stat + xpose + rowdots + weight transposes
    prep_conv<<<1984, 512, 0, stream>>>(dyn, dyn16, ipW, ipb, ipWq16, ipWkv16,
                                        ctx_W, ctxW16, statIn, stat_W, stat_b,
                                        st_g, st16, x, xT16,
                                        q_W, qWT16, dyn_W, dynWT16, out_W, outWT16,
                                        q_b, qb2, dyn_b, bkv2, out_b, ctx_b, cb2);
    // 2. weight folds on MFMA + film1
    gemm_fold3<<<176, 256, 0, stream>>>(ipWq16, qWT16, WqW16,
                                        ipWkv16, dynWT16, Wkv216,
                                        ctxW16, outWT16, M216,
                                        st_g, fW1, fb1, h1_g);
    // 3. merged q + kv GEMMs (pipelined, XCD-swizzled) + film2
    gemm_qkv<<<1608, 256, 0, stream>>>(xT16, WqW16, qb2, q16,
                                       dyn16, st16, Wkv216, ipWkv16, bkv2, ipbkv,
                                       k16, vtmp, h1_g, fW2, fb2, scaleB);
    // 4. V transpose -> vT16
    vtrans_kernel<<<dim3(17, 8, B_), 256, 0, stream>>>(vtmp, vT16);
    // 5. flash attention -> ctx16
    attn_mfma_kernel<<<1024, 256, 0, stream>>>(q16, k16, vT16, bt, ctx16);
    // 6. final: 64x128 tiles, 512 blocks
    gemm_final<<<dim3(H_ / 128, C_ / 64, B_), 256, 0, stream>>>(
        M216, ctx16, cb2, out, x, scaleB);
}